// Round 2
// baseline (335.445 us; speedup 1.0000x reference)
//
#include <hip/hip_runtime.h>
#include <math.h>

#define N 256
#define PSTR 260   // per-wave stride in part[] (mult. of 4 -> b128-aligned; 260%32=4 rotates banks)

// xor-swizzle within 32-lane half (single ds_swizzle instr, no VALU addr calc)
template<int XM>
__device__ __forceinline__ float swz(float v) {
  int i = __builtin_amdgcn_ds_swizzle(__builtin_bit_cast(int, v), (XM << 10) | 0x1F);
  return __builtin_bit_cast(float, i);
}
// sum over the 32 lanes sharing ti (tj butterfly) -> all lanes get identical full sum
__device__ __forceinline__ float half_sum(float v) {
  v += swz<1>(v); v += swz<2>(v); v += swz<4>(v); v += swz<8>(v); v += swz<16>(v);
  return v;
}
__device__ __forceinline__ float wave_sum(float v) {
  v = half_sum(v); v += __shfl_xor(v, 32); return v;
}
__device__ __forceinline__ float wave_max(float v) {
  v = fmaxf(v, swz<1>(v)); v = fmaxf(v, swz<2>(v)); v = fmaxf(v, swz<4>(v));
  v = fmaxf(v, swz<8>(v)); v = fmaxf(v, swz<16>(v)); v = fmaxf(v, __shfl_xor(v, 32));
  return v;
}
__device__ __forceinline__ float wave_min(float v) {
  v = fminf(v, swz<1>(v)); v = fminf(v, swz<2>(v)); v = fminf(v, swz<4>(v));
  v = fminf(v, swz<8>(v)); v = fminf(v, swz<16>(v)); v = fminf(v, __shfl_xor(v, 32));
  return v;
}

__global__ __launch_bounds__(1024, 4) void icvp_kernel(
    const float* __restrict__ X, const float* __restrict__ A,
    const float* __restrict__ Bv, float* __restrict__ out)
{
  const int p    = blockIdx.x;
  const int t    = threadIdx.x;
  const int ti   = t >> 5;          // row-block 0..31 (rows ti*8..+8)
  const int tj   = t & 31;          // col-block 0..31 (cols tj*8..+8)
  const int w    = t >> 6;          // wave 0..15
  const int lane = t & 63;
  const int q    = t & 3;           // quarter within col-group
  const int colr = t >> 2;          // column this thread reduces (0..255)

  __shared__ __align__(16) float part[16 * PSTR]; // [wave][col] transpose partials
  __shared__ __align__(16) float xn[N];           // current x
  __shared__ __align__(16) float x0n[N];          // original x
  __shared__ __align__(16) float gn[N];           // power-iter vector staging
  __shared__ float wsc[16], wsc2[16], scal[4];

  // ---- load A tile: 8x8 fp32 per thread ----
  float Areg[8][8];
  {
    const float* Ap = A + (size_t)p * (N * N);
    #pragma unroll
    for (int r = 0; r < 8; ++r) {
      const float4* src = reinterpret_cast<const float4*>(Ap + (ti * 8 + r) * N + tj * 8);
      float4 a0 = src[0], a1 = src[1];
      Areg[r][0] = a0.x; Areg[r][1] = a0.y; Areg[r][2] = a0.z; Areg[r][3] = a0.w;
      Areg[r][4] = a1.x; Areg[r][5] = a1.y; Areg[r][6] = a1.z; Areg[r][7] = a1.w;
    }
  }
  if (t < N) { float xv = X[p * N + t]; xn[t] = xv; x0n[t] = xv; }

  // ---- row norms (in-wave butterfly), scale A, b_tight in registers ----
  float btl[8];
  {
    const float4* bp = reinterpret_cast<const float4*>(Bv + p * N + ti * 8);
    float4 b0 = bp[0], b1 = bp[1];
    float bl[8] = {b0.x, b0.y, b0.z, b0.w, b1.x, b1.y, b1.z, b1.w};
    #pragma unroll
    for (int r = 0; r < 8; ++r) {
      float s = 0.f;
      #pragma unroll
      for (int c = 0; c < 8; ++c) s = fmaf(Areg[r][c], Areg[r][c], s);
      s = half_sum(s);
      float inv = 1.0f / fmaxf(sqrtf(s), 1e-12f);
      #pragma unroll
      for (int c = 0; c < 8; ++c) Areg[r][c] *= inv;
      btl[r] = bl[r] * inv - 1e-3f;    // b_w - MU_INSIDE
    }
  }

  // ---- power iteration (5 iters) ----
  float vloc[8];
  #pragma unroll
  for (int c = 0; c < 8; ++c) vloc[c] = 0.0625f;  // ones/||ones|| exact

  for (int pit = 0; pit < 5; ++pit) {
    float av[8];
    #pragma unroll
    for (int r = 0; r < 8; ++r) {
      float s = 0.f;
      #pragma unroll
      for (int c = 0; c < 8; ++c) s = fmaf(Areg[r][c], vloc[c], s);
      av[r] = half_sum(s);                       // full (A v)[row], own rows
    }
    float gc[8];
    #pragma unroll
    for (int c = 0; c < 8; ++c) {
      float s = 0.f;
      #pragma unroll
      for (int r = 0; r < 8; ++r) s = fmaf(Areg[r][c], av[r], s);
      s += __shfl_xor(s, 32);                    // fold the two ti-halves
      gc[c] = s;
    }
    if (lane < 32) {
      float4* dst = reinterpret_cast<float4*>(&part[w * PSTR + tj * 8]);
      dst[0] = make_float4(gc[0], gc[1], gc[2], gc[3]);
      dst[1] = make_float4(gc[4], gc[5], gc[6], gc[7]);
    }
    __syncthreads();
    float g = (part[(q * 4 + 0) * PSTR + colr] + part[(q * 4 + 1) * PSTR + colr])
            + (part[(q * 4 + 2) * PSTR + colr] + part[(q * 4 + 3) * PSTR + colr]);
    g += __shfl_xor(g, 1); g += __shfl_xor(g, 2);  // full AtAv[colr]
    float ss = (q == 0) ? g * g : 0.f;
    ss = wave_sum(ss);
    if (lane == 0) wsc[w] = ss;
    if (q == 0) gn[colr] = g;
    __syncthreads();
    if (t == 0) {
      float s = 0.f;
      #pragma unroll
      for (int i = 0; i < 16; ++i) s += wsc[i];
      scal[0] = sqrtf(s) + 1e-12f;
    }
    __syncthreads();
    {
      const float4* gp = reinterpret_cast<const float4*>(&gn[tj * 8]);
      float4 g0 = gp[0], g1 = gp[1];
      float den = scal[0];
      vloc[0] = g0.x / den; vloc[1] = g0.y / den; vloc[2] = g0.z / den; vloc[3] = g0.w / den;
      vloc[4] = g1.x / den; vloc[5] = g1.y / den; vloc[6] = g1.z / den; vloc[7] = g1.w / den;
    }
  }
  // eta = 1/(sum((A v)^2) + rho); rows duplicated x32 in-wave -> divide by 32 (exact)
  {
    float ss = 0.f;
    #pragma unroll
    for (int r = 0; r < 8; ++r) {
      float s = 0.f;
      #pragma unroll
      for (int c = 0; c < 8; ++c) s = fmaf(Areg[r][c], vloc[c], s);
      s = half_sum(s);
      ss = fmaf(s, s, ss);
    }
    ss = wave_sum(ss);     // = 32 * (this wave's 16 rows' sum of squares)
    if (lane == 0) wsc[w] = ss;
    __syncthreads();
    if (t == 0) {
      float s = 0.f;
      #pragma unroll
      for (int i = 0; i < 16; ++i) s += wsc[i];
      scal[1] = 1.0f / (s * 0.03125f + 1e-12f);
    }
    __syncthreads();
  }
  const float eta = scal[1];

  // ---- UVP: 30 iterations, 2 barriers each ----
  float xloc[8];
  {
    const float4* xp = reinterpret_cast<const float4*>(&xn[tj * 8]);
    float4 x0 = xp[0], x1 = xp[1];
    xloc[0] = x0.x; xloc[1] = x0.y; xloc[2] = x0.z; xloc[3] = x0.w;
    xloc[4] = x1.x; xloc[5] = x1.y; xloc[6] = x1.z; xloc[7] = x1.w;
  }
  for (int k = 0; k < 30; ++k) {
    float rl[8];
    #pragma unroll
    for (int r = 0; r < 8; ++r) {
      float s = 0.f;
      #pragma unroll
      for (int c = 0; c < 8; ++c) s = fmaf(Areg[r][c], xloc[c], s);
      s = half_sum(s);
      rl[r] = fmaxf(s - btl[r], 0.f);            // relu(Ax - b_tight), own rows
    }
    float gc[8];
    #pragma unroll
    for (int c = 0; c < 8; ++c) {
      float s = 0.f;
      #pragma unroll
      for (int r = 0; r < 8; ++r) s = fmaf(Areg[r][c], rl[r], s);
      s += __shfl_xor(s, 32);
      gc[c] = s;
    }
    if (lane < 32) {
      float4* dst = reinterpret_cast<float4*>(&part[w * PSTR + tj * 8]);
      dst[0] = make_float4(gc[0], gc[1], gc[2], gc[3]);
      dst[1] = make_float4(gc[4], gc[5], gc[6], gc[7]);
    }
    __syncthreads();
    float g = (part[(q * 4 + 0) * PSTR + colr] + part[(q * 4 + 1) * PSTR + colr])
            + (part[(q * 4 + 2) * PSTR + colr] + part[(q * 4 + 3) * PSTR + colr]);
    g += __shfl_xor(g, 1); g += __shfl_xor(g, 2);
    if (q == 0) xn[colr] = xn[colr] - eta * g;
    __syncthreads();
    {
      const float4* xp = reinterpret_cast<const float4*>(&xn[tj * 8]);
      float4 x0 = xp[0], x1 = xp[1];
      xloc[0] = x0.x; xloc[1] = x0.y; xloc[2] = x0.z; xloc[3] = x0.w;
      xloc[4] = x1.x; xloc[5] = x1.y; xloc[6] = x1.z; xloc[7] = x1.w;
    }
  }

  // ---- stage 2: gate + alpha, all in-wave ----
  float dloc[8];
  {
    const float4* xp = reinterpret_cast<const float4*>(&x0n[tj * 8]);
    float4 x0 = xp[0], x1 = xp[1];
    dloc[0] = x0.x - xloc[0]; dloc[1] = x0.y - xloc[1];
    dloc[2] = x0.z - xloc[2]; dloc[3] = x0.w - xloc[3];
    dloc[4] = x1.x - xloc[4]; dloc[5] = x1.y - xloc[5];
    dloc[6] = x1.z - xloc[6]; dloc[7] = x1.w - xloc[7];
  }
  float mv = 0.f, aim = INFINITY;
  #pragma unroll
  for (int r = 0; r < 8; ++r) {
    float sx = 0.f, sd = 0.f;
    #pragma unroll
    for (int c = 0; c < 8; ++c) {
      sx = fmaf(Areg[r][c], xloc[c], sx);
      sd = fmaf(Areg[r][c], dloc[c], sd);
    }
    float ax = half_sum(sx);
    float ad = half_sum(sd);
    float bw = btl[r] + 1e-3f;                    // recover b_w
    mv = fmaxf(mv, ax - bw);
    float ai = (ad > 0.f) ? (bw - ax) / (ad + 1e-12f) : INFINITY;
    aim = fminf(aim, ai);
  }
  mv = fmaxf(mv, 0.f);
  mv  = wave_max(mv);
  aim = wave_min(aim);
  if (lane == 0) { wsc[w] = mv; wsc2[w] = aim; }
  __syncthreads();
  if (t == 0) {
    float M = 0.f, Al = INFINITY;
    #pragma unroll
    for (int i = 0; i < 16; ++i) { M = fmaxf(M, wsc[i]); Al = fminf(Al, wsc2[i]); }
    if (!isfinite(Al)) Al = 1.0f;
    Al = fminf(fmaxf(Al - 1e-6f, 0.f), 1.0f);
    scal[2] = M; scal[3] = Al;
  }
  __syncthreads();
  if (t < N) {
    float xv = xn[t];
    float d  = x0n[t] - xv;
    bool da  = (scal[2] <= 1e-7f);
    out[p * N + t] = da ? fmaf(scal[3], d, xv) : xv;
  }
}

extern "C" void kernel_launch(void* const* d_in, const int* in_sizes, int n_in,
                              void* d_out, int out_size, void* d_ws, size_t ws_size,
                              hipStream_t stream) {
  const float* X  = (const float*)d_in[0];
  const float* A  = (const float*)d_in[1];
  const float* Bv = (const float*)d_in[2];
  float* out = (float*)d_out;
  const int nprob = in_sizes[0] / N;   // 512
  icvp_kernel<<<nprob, 1024, 0, stream>>>(X, A, Bv, out);
}

// Round 3
// 289.746 us; speedup vs baseline: 1.1577x; 1.1577x over previous
//
#include <hip/hip_runtime.h>
#include <math.h>

#define N 256

// xor-swizzle within 32-lane half (DS pipe, 1 instr)
template<int XM>
__device__ __forceinline__ float swz(float v) {
  int i = __builtin_amdgcn_ds_swizzle(__builtin_bit_cast(int, v), (XM << 10) | 0x1F);
  return __builtin_bit_cast(float, i);
}
// DPP lane-shuffle (VALU pipe, not DS)
template<int CTRL>
__device__ __forceinline__ float dppmv(float v) {
  int y = __builtin_amdgcn_update_dpp(0, __builtin_bit_cast(int, v), CTRL, 0xF, 0xF, true);
  return __builtin_bit_cast(float, y);
}
// sum over 32-lane half: 4 VALU rotate-adds + 1 swizzle; all lanes get the sum
__device__ __forceinline__ float red32s(float v) {
  v += dppmv<0x121>(v);   // row_ror:1
  v += dppmv<0x122>(v);   // row_ror:2
  v += dppmv<0x124>(v);   // row_ror:4
  v += dppmv<0x128>(v);   // row_ror:8  -> 16-lane row sum, all lanes
  v += swz<16>(v);        // cross the two 16-rows of the 32-half
  return v;
}

__global__ __launch_bounds__(1024, 4) void icvp_kernel(
    const float* __restrict__ X, const float* __restrict__ A,
    const float* __restrict__ Bv, float* __restrict__ out)
{
  const int p     = blockIdx.x;
  const int t     = threadIdx.x;
  const int w     = t >> 6;
  const int lane  = t & 63;
  const int h     = lane >> 5;
  const int j     = lane & 31;       // col-block within group
  const int G     = w * 2 + h;       // row-group: owns rows G*8..+8
  const int c_red = t >> 2;          // reducer: column owned (x4 dup over h4)
  const int h4    = t & 3;
  const int chnk  = c_red >> 3;
  const int coff  = c_red & 7;

  __shared__ __align__(16) float part[32 * 256];   // [group][xor-swizzled col]
  __shared__ __align__(16) float xn[N], x0n[N], gn[N];
  __shared__ float wsc[16], wsc2[16], scal[4];

  // ---- A tile: rows G*8..+8, cols j*8..+8 (64 fp32 in regs) ----
  float Areg[8][8];
  {
    const float* Ap = A + (size_t)p * (N * N) + (G * 8) * N + j * 8;
    #pragma unroll
    for (int r = 0; r < 8; ++r) {
      const float4* src = reinterpret_cast<const float4*>(Ap + r * N);
      float4 a0 = src[0], a1 = src[1];
      Areg[r][0]=a0.x; Areg[r][1]=a0.y; Areg[r][2]=a0.z; Areg[r][3]=a0.w;
      Areg[r][4]=a1.x; Areg[r][5]=a1.y; Areg[r][6]=a1.z; Areg[r][7]=a1.w;
    }
  }
  if (t < N) { float xv = X[p * N + t]; xn[t] = xv; x0n[t] = xv; }

  // ---- row norms (DPP reduce), scale A, b_tight in regs ----
  float btl[8];
  {
    const float4* bp = reinterpret_cast<const float4*>(Bv + p * N + G * 8);
    float4 b0 = bp[0], b1 = bp[1];
    float bl[8] = {b0.x,b0.y,b0.z,b0.w,b1.x,b1.y,b1.z,b1.w};
    #pragma unroll
    for (int r = 0; r < 8; ++r) {
      float s = 0.f;
      #pragma unroll
      for (int c = 0; c < 8; ++c) s = fmaf(Areg[r][c], Areg[r][c], s);
      s = red32s(s);
      float inv = 1.0f / fmaxf(sqrtf(s), 1e-12f);
      #pragma unroll
      for (int c = 0; c < 8; ++c) Areg[r][c] *= inv;
      btl[r] = bl[r] * inv - 1e-3f;     // b_w - MU_INSIDE
    }
  }

  // ---- helpers ----
  auto fwd8 = [&](const float (&vv)[8], float (&s)[8]) {  // s[r] = full (A vv)[G*8+r]
    #pragma unroll
    for (int r = 0; r < 8; ++r) {
      float a = 0.f;
      #pragma unroll
      for (int c = 0; c < 8; ++c) a = fmaf(Areg[r][c], vv[c], a);
      s[r] = a;
    }
    #pragma unroll
    for (int r = 0; r < 8; ++r) s[r] = red32s(s[r]);
  };
  auto trans_write = [&](const float (&rr)[8]) {  // in-lane A^T partial, xor-swizzled b128 store
    float gp0[8];
    #pragma unroll
    for (int c = 0; c < 8; ++c) {
      float a = 0.f;
      #pragma unroll
      for (int r2 = 0; r2 < 8; ++r2) a = fmaf(Areg[r2][c], rr[r2], a);
      gp0[c] = a;
    }
    float4* dst = reinterpret_cast<float4*>(&part[(G << 8) + (((j ^ G) & 31) << 3)]);
    dst[0] = make_float4(gp0[0], gp0[1], gp0[2], gp0[3]);
    dst[1] = make_float4(gp0[4], gp0[5], gp0[6], gp0[7]);
  };
  auto col_reduce = [&]() {  // 8 b32 reads (2-way banks) + 2 quad_perm folds
    float g = 0.f;
    #pragma unroll
    for (int i = 0; i < 8; ++i) {
      const int grp = h4 + 4 * i;
      g += part[(grp << 8) + (((chnk ^ grp) & 31) << 3) + coff];
    }
    g += dppmv<0xB1>(g);   // fold lane^1 (quad_perm [1,0,3,2])
    g += dppmv<0x4E>(g);   // fold lane^2 (quad_perm [2,3,0,1])
    return g;              // full A^T-vec at column c_red (x4 dup, bitwise identical)
  };
  auto load8v = [&](const float* base, float (&d)[8]) {   // 2 b128 broadcast-ish reads
    const float4* v4 = reinterpret_cast<const float4*>(base + j * 8);
    float4 a0 = v4[0], a1 = v4[1];
    d[0]=a0.x; d[1]=a0.y; d[2]=a0.z; d[3]=a0.w; d[4]=a1.x; d[5]=a1.y; d[6]=a1.z; d[7]=a1.w;
  };

  // ---- power iteration (5 iters) ----
  float vloc[8];
  #pragma unroll
  for (int c = 0; c < 8; ++c) vloc[c] = 0.0625f;   // ones/||ones|| exact

  for (int pit = 0; pit < 5; ++pit) {
    float av[8];
    fwd8(vloc, av);
    trans_write(av);
    __syncthreads();
    float g = col_reduce();                 // AtAv[c_red]
    if (h4 == 0) gn[c_red] = g;
    float ss = (h4 == 0) ? g * g : 0.f;
    ss = red32s(ss); ss += __shfl_xor(ss, 32);
    if (lane == 0) wsc[w] = ss;
    __syncthreads();
    if (t == 0) {
      float s = 0.f;
      #pragma unroll
      for (int i = 0; i < 16; ++i) s += wsc[i];
      scal[0] = sqrtf(s) + 1e-12f;
    }
    __syncthreads();
    load8v(gn, vloc);
    {
      float den = scal[0];
      #pragma unroll
      for (int c = 0; c < 8; ++c) vloc[c] /= den;
    }
  }
  // eta = 1/(sum((A v)^2) + rho)
  {
    float av[8];
    fwd8(vloc, av);
    float ss = 0.f;
    #pragma unroll
    for (int r = 0; r < 8; ++r) ss = fmaf(av[r], av[r], ss);  // group-uniform
    ss += __shfl_xor(ss, 32);
    if (lane == 0) wsc[w] = ss;
    __syncthreads();
    if (t == 0) {
      float s = 0.f;
      #pragma unroll
      for (int i = 0; i < 16; ++i) s += wsc[i];
      scal[1] = 1.0f / (s + 1e-12f);
    }
    __syncthreads();
  }
  const float eta = scal[1];

  // ---- UVP: 30 iterations, 2 barriers each ----
  float xloc[8];
  load8v(xn, xloc);
  float xred = xn[c_red];
  for (int k = 0; k < 30; ++k) {
    float s[8];
    fwd8(xloc, s);
    float rl[8];
    #pragma unroll
    for (int r = 0; r < 8; ++r) rl[r] = fmaxf(s[r] - btl[r], 0.f);
    trans_write(rl);
    __syncthreads();
    float g = col_reduce();
    xred = fmaf(-eta, g, xred);
    if (h4 == 0) xn[c_red] = xred;
    __syncthreads();
    load8v(xn, xloc);
  }

  // ---- stage 2: gate + alpha ----
  float x0loc[8], dloc[8];
  load8v(x0n, x0loc);
  #pragma unroll
  for (int c = 0; c < 8; ++c) dloc[c] = x0loc[c] - xloc[c];
  float sx[8], sd[8];
  fwd8(xloc, sx);
  fwd8(dloc, sd);
  float mv = -INFINITY, aim = INFINITY;
  #pragma unroll
  for (int r = 0; r < 8; ++r) {
    float bw = btl[r] + 1e-3f;
    float ax = sx[r], ad = sd[r];
    mv = fmaxf(mv, ax - bw);
    float ai = (ad > 0.f) ? (bw - ax) / (ad + 1e-12f) : INFINITY;
    aim = fminf(aim, ai);
  }
  // mv/aim are group-uniform; fold across the wave's two groups
  mv  = fmaxf(mv,  __shfl_xor(mv, 32));
  aim = fminf(aim, __shfl_xor(aim, 32));
  if (lane == 0) { wsc[w] = mv; wsc2[w] = aim; }
  __syncthreads();
  if (t == 0) {
    float M = -INFINITY, Al = INFINITY;
    #pragma unroll
    for (int i = 0; i < 16; ++i) { M = fmaxf(M, wsc[i]); Al = fminf(Al, wsc2[i]); }
    if (!isfinite(Al)) Al = 1.0f;
    Al = fminf(fmaxf(Al - 1e-6f, 0.f), 1.0f);
    scal[2] = M; scal[3] = Al;
  }
  __syncthreads();
  if (t < N) {
    float xv = xn[t];
    float d  = x0n[t] - xv;
    out[p * N + t] = (scal[2] <= 1e-7f) ? fmaf(scal[3], d, xv) : xv;
  }
}

extern "C" void kernel_launch(void* const* d_in, const int* in_sizes, int n_in,
                              void* d_out, int out_size, void* d_ws, size_t ws_size,
                              hipStream_t stream) {
  const float* X  = (const float*)d_in[0];
  const float* A  = (const float*)d_in[1];
  const float* Bv = (const float*)d_in[2];
  float* out = (float*)d_out;
  const int nprob = in_sizes[0] / N;   // 512
  icvp_kernel<<<nprob, 1024, 0, stream>>>(X, A, Bv, out);
}